// Round 4
// baseline (148.827 us; speedup 1.0000x reference)
//
#include <hip/hip_runtime.h>
#include <stdint.h>
#include <stddef.h>

// ---- problem constants ----
#define K_CODES 1024
#define D_DIM   256
#define HW      1024      // 32*32 spatial
#define N_VEC   32768
#define TOT_ELEMS 8388608
#define NBLK    512       // vq_main grid

typedef float    v4f __attribute__((ext_vector_type(4)));
typedef _Float16 v8h __attribute__((ext_vector_type(8)));

// async global->LDS, 16B/lane, dest = wave-uniform base + lane*16
__device__ __forceinline__ void gld_lds16(const void* g, void* l) {
    __builtin_amdgcn_global_load_lds(
        (const __attribute__((address_space(1))) void*)g,
        (__attribute__((address_space(3))) void*)l, 16, 0, 0);
}

// ------------------------------------------------------------------
// K1: codebook -> fp16 copy + 0.5*||e||^2 (+ zero loss_acc & counter).
__global__ void prep_emb(const float* __restrict__ emb,
                         _Float16* __restrict__ emb_h,
                         float* __restrict__ hnorm,
                         float* __restrict__ loss_acc,
                         unsigned* __restrict__ cnt) {
    int k = blockIdx.x, t = threadIdx.x;
    if (k == 0 && t == 0) { loss_acc[0] = 0.f; cnt[0] = 0u; }
    float v = emb[(size_t)k * D_DIM + t];
    emb_h[(size_t)k * D_DIM + t] = (_Float16)v;
    float s = v * v;
    for (int off = 32; off; off >>= 1) s += __shfl_down(s, off);
    __shared__ float wsum[4];
    if ((t & 63) == 0) wsum[t >> 6] = s;
    __syncthreads();
    if (t == 0) hnorm[k] = 0.5f * (wsum[0] + wsum[1] + wsum[2] + wsum[3]);
}

// ------------------------------------------------------------------
// K2: fully fused VQ. 512 blocks x 512 thr (8 waves), 64 rows/block.
// 2 blocks/CU resident (LDS ~71 KB, natural ~92 VGPR via (512,2)).
// 8 waves = 4 code-quarters (grp: 256 codes each) x 2 row-halves (wv:
// 32 rows each, af0+af1 => bf reused for 2 row-tiles, ds:MFMA = 1:2).
// Codebook tiles: 16 codes (8 KB), double-buffered per quarter
// (btile = 4 grp x 2 buf x 8 KB = 64 KB). dist' = 0.5||e||^2 - <z,e>.
// Swizzle: granule g of code k stored at slot u = g ^ (k&7); inherent
// 4 extra cyc per ds_read_b128 is b128's 4-phase cost, not a conflict.
// 4-way in-block argmin merge (ascending grp, strict < => lowest idx).
// Finalize folded in via last-block-done ticket (cnt zeroed by K1).
__global__ __launch_bounds__(512, 2) void
vq_main(const float* __restrict__ z,
        const _Float16* __restrict__ emb_h,
        const float* __restrict__ emb,
        const float* __restrict__ hnorm,
        float* __restrict__ out,
        float* __restrict__ loss_acc,
        unsigned* __restrict__ cnt) {
    // btile 64 KB; epilogue zq overlays (32 x 257 floats = 32896 B).
    __shared__ __align__(16) char smem[65536];
    __shared__ float  norm_s[K_CODES];
    __shared__ int    idx_s[64];
    __shared__ float2 mrg[3][2][32];
    __shared__ float  wred[8];

    int t    = threadIdx.x;
    int wave = t >> 6;
    int lane = t & 63;
    int grp  = wave >> 1;     // code quarter 0..3
    int wv   = wave & 1;      // 32-row half
    int col  = lane & 15;
    int quad = lane >> 4;
    int b    = blockIdx.x >> 4;
    int hw0  = (blockIdx.x & 15) * 64;
    const float* zb = z + (size_t)b * D_DIM * HW;

    // stage tile T (16 codes, 8 KB) of this wave's quarter; the two
    // waves sharing a quarter (wv 0/1) each stage 8 codes (4 KB).
    auto stage = [&](int buf, int T) {
        const char* src = (const char*)emb_h
                          + (size_t)(grp * 256 + T * 16) * 512;
        char* dst = (char*)smem + (grp * 2 + buf) * 8192 + wv * 4096;
#pragma unroll
        for (int i = 0; i < 4; ++i) {
            int kloc = wv * 8 + i * 2 + (lane >> 5);
            int g    = (lane & 31) ^ (kloc & 7);
            gld_lds16(src + (size_t)kloc * 512 + (size_t)g * 16,
                      dst + i * 1024);
        }
    };
    stage(0, 0);

    for (int i = t; i < K_CODES; i += 512) norm_s[i] = hnorm[i];

    // A fragments: 32 rows/wave (af0: rows m0.., af1: rows m0+16..)
    int m0 = hw0 + wv * 32;
    v8h af0[8], af1[8];
#pragma unroll
    for (int c = 0; c < 8; ++c) {
#pragma unroll
        for (int j = 0; j < 8; ++j) {
            int d = c * 32 + quad * 8 + j;
            const float* p = zb + (size_t)d * HW + m0 + col;
            af0[c][j] = (_Float16)p[0];
            af1[c][j] = (_Float16)p[16];
        }
    }

    float minv[8]; int mini[8];
#pragma unroll
    for (int r = 0; r < 8; ++r) { minv[r] = 3.4e38f; mini[r] = 0; }

    for (int T = 0; T < 16; ++T) {
        __syncthreads();                 // staged buffer ready
        if (T < 15) stage((T + 1) & 1, T + 1);
        const _Float16* bt =
            (const _Float16*)(smem + (size_t)(grp * 2 + (T & 1)) * 8192);
        v8h bf[8];
#pragma unroll
        for (int c = 0; c < 8; ++c) {
            int u = (c * 4 + quad) ^ (col & 7);   // k&7 == col&7
            bf[c] = *(const v8h*)(bt + (size_t)col * D_DIM + (u << 3));
        }
        v4f acc0 = {0.f, 0.f, 0.f, 0.f};
        v4f acc1 = {0.f, 0.f, 0.f, 0.f};
#pragma unroll
        for (int c = 0; c < 8; ++c) {
            acc0 = __builtin_amdgcn_mfma_f32_16x16x32_f16(af0[c], bf[c], acc0, 0, 0, 0);
            acc1 = __builtin_amdgcn_mfma_f32_16x16x32_f16(af1[c], bf[c], acc1, 0, 0, 0);
        }
        int   code = grp * 256 + T * 16 + col;
        float n    = norm_s[code];
#pragma unroll
        for (int r = 0; r < 4; ++r) {
            float d0 = n - acc0[r];
            if (d0 < minv[r])     { minv[r]     = d0; mini[r]     = code; }
            float d1 = n - acc1[r];
            if (d1 < minv[4 + r]) { minv[4 + r] = d1; mini[4 + r] = code; }
        }
    }
    // reduce across the 16 cols of each quad
#pragma unroll
    for (int off = 1; off < 16; off <<= 1) {
#pragma unroll
        for (int r = 0; r < 8; ++r) {
            float ov = __shfl_xor(minv[r], off);
            int   oi = __shfl_xor(mini[r], off);
            if (ov < minv[r] || (ov == minv[r] && oi < mini[r])) {
                minv[r] = ov; mini[r] = oi;
            }
        }
    }
    // 4-way quarter merge: grp 1..3 post, grp 0 merges in ascending
    // code order (strict < keeps lowest index).
    if (grp != 0 && col == 0) {
#pragma unroll
        for (int r = 0; r < 8; ++r) {
            int rl = (r >> 2) * 16 + quad * 4 + (r & 3);
            mrg[grp - 1][wv][rl] = make_float2(minv[r], __int_as_float(mini[r]));
        }
    }
    __syncthreads();
    if (grp == 0 && col == 0) {
#pragma unroll
        for (int r = 0; r < 8; ++r) {
            int rl = (r >> 2) * 16 + quad * 4 + (r & 3);
            float bv = minv[r]; int bi = mini[r];
#pragma unroll
            for (int h = 0; h < 3; ++h) {
                float2 m2 = mrg[h][wv][rl];
                if (m2.x < bv) { bv = m2.x; bi = __float_as_int(m2.y); }
            }
            idx_s[wv * 32 + rl] = bi;
        }
    }
    __syncthreads();

    // ---- epilogue: gather emb rows -> LDS, write out + fused loss ----
    // 64 rows in two 32-row passes; all 8 waves cooperate.
    float* zq = (float*)smem;                 // 32 x 257 floats
    int tt = t & 255, th = t >> 8;            // th in {0,1}
    float sum = 0.f;
    for (int s = 0; s < 2; ++s) {
        if (s) __syncthreads();
#pragma unroll
        for (int ii = 0; ii < 16; ++ii) {
            int i = th * 16 + ii;
            zq[i * 257 + tt] =
                emb[(size_t)idx_s[s * 32 + i] * D_DIM + tt];
        }
        __syncthreads();
        int j = t & 31, dblk = t >> 5;        // dblk 0..15
#pragma unroll
        for (int p = 0; p < 16; ++p) {
            int d = dblk * 16 + p;
            size_t o = (size_t)(b * D_DIM + d) * HW
                       + hw0 + s * 32 + j;
            float q  = zq[j * 257 + d];
            float e  = z[o];
            float df = q - e;
            sum += df * df;
            out[o] = q;                 // z_q_st == z_q numerically
        }
    }
    for (int off = 32; off; off >>= 1) sum += __shfl_down(sum, off);
    if (lane == 0) wred[wave] = sum;
    __syncthreads();
    if (t == 0) {
        float s8 = 0.f;
#pragma unroll
        for (int i = 0; i < 8; ++i) s8 += wred[i];
        atomicAdd(loss_acc, s8);
        __threadfence();
        if (atomicAdd(cnt, 1u) == NBLK - 1) {
            // all blocks' loss adds are visible at the L2 atomic point
            float total = atomicAdd(loss_acc, 0.0f);
            out[TOT_ELEMS] = total * (1.25f / (float)TOT_ELEMS);
        }
    }
}

// ------------------------------------------------------------------
extern "C" void kernel_launch(void* const* d_in, const int* in_sizes, int n_in,
                              void* d_out, int out_size, void* d_ws, size_t ws_size,
                              hipStream_t stream) {
    const float* z   = (const float*)d_in[0];   // [32,256,32,32]
    const float* emb = (const float*)d_in[1];   // [1024,256]
    float* out = (float*)d_out;                 // [8388608 z_q_st][1 loss]

    char* ws = (char*)d_ws;
    float*    loss_acc = (float*)ws;            // @0
    unsigned* cnt      = (unsigned*)(ws + 4);   // last-block ticket
    float*    hnorm    = (float*)(ws + 1024);   // 4 KB
    _Float16* emb_h    = (_Float16*)(ws + 8192);// 512 KB

    prep_emb<<<dim3(K_CODES), dim3(256), 0, stream>>>(emb, emb_h, hnorm,
                                                      loss_acc, cnt);
    vq_main<<<dim3(NBLK), dim3(512), 0, stream>>>(z, emb_h, emb, hnorm,
                                                  out, loss_acc, cnt);
}